// Round 1
// baseline (1399.717 us; speedup 1.0000x reference)
//
#include <hip/hip_runtime.h>
#include <hip/hip_bf16.h>
#include <math.h>

#define N_NODES 100000
#define N_EDGES 1600000
#define F_IN 64
#define H_DIM 200
#define N_GRAPHS 512

// ---------------- CSR build (bucket edges by dst) ----------------
__global__ void hist_kernel(const int* __restrict__ ei, int* __restrict__ cnt) {
    int i = blockIdx.x * blockDim.x + threadIdx.x;
    if (i < N_EDGES) atomicAdd(&cnt[ei[N_EDGES + i]], 1);
}

// single block of 1024 threads: exclusive prefix sum over degree array.
// cnt: in = per-node degree, out = running start offsets (cursor for fill).
// ptr: CSR row pointers [N+1].
__global__ void scan_kernel(int* __restrict__ cnt, int* __restrict__ ptr) {
    __shared__ int sums[1024];
    int t = threadIdx.x;
    const int per = (N_NODES + 1023) / 1024;   // 98
    int start = t * per;
    int end = start + per; if (end > N_NODES) end = N_NODES;
    if (start > N_NODES) start = N_NODES;
    int s = 0;
    for (int i = start; i < end; ++i) s += cnt[i];
    sums[t] = s;
    __syncthreads();
    for (int off = 1; off < 1024; off <<= 1) {
        int v = sums[t];
        int add = (t >= off) ? sums[t - off] : 0;
        __syncthreads();
        sums[t] = v + add;
        __syncthreads();
    }
    int run = sums[t] - s;   // exclusive prefix for this chunk
    for (int i = start; i < end; ++i) {
        int d = cnt[i];
        ptr[i] = run;
        cnt[i] = run;
        run += d;
    }
    if (t == 1023) ptr[N_NODES] = sums[1023];
}

__global__ void fill_kernel(const int* __restrict__ ei, int* __restrict__ cursor,
                            int* __restrict__ csr_src) {
    int i = blockIdx.x * blockDim.x + threadIdx.x;
    if (i < N_EDGES) {
        int s = ei[i];
        int d = ei[N_EDGES + i];
        int p = atomicAdd(&cursor[d], 1);
        csr_src[p] = s;
    }
}

// ---------------- Aggregation layer 1: 64-dim rows, one wave per node ----------------
__global__ __launch_bounds__(256) void agg1_kernel(const float* __restrict__ x,
        const int* __restrict__ ptr, const int* __restrict__ src,
        const float* __restrict__ eps_p, float* __restrict__ agg) {
    int node = blockIdx.x * 4 + (threadIdx.x >> 6);
    int lane = threadIdx.x & 63;
    if (node >= N_NODES) return;
    float acc = (1.0f + eps_p[0]) * x[(size_t)node * 64 + lane];
    int b = ptr[node], e = ptr[node + 1];
    for (int j = b; j < e; ++j) {
        int s = src[j];                       // wave-uniform load
        acc += x[(size_t)s * 64 + lane];      // coalesced 256B row
    }
    agg[(size_t)node * 64 + lane] = acc;
}

// ---------------- Aggregation layer 2: 200-dim rows, one wave per node, float4 lanes ----------------
__global__ __launch_bounds__(256) void agg2_kernel(const float* __restrict__ h,
        const int* __restrict__ ptr, const int* __restrict__ src,
        const float* __restrict__ eps_p, float* __restrict__ agg) {
    int node = blockIdx.x * 4 + (threadIdx.x >> 6);
    int lane = threadIdx.x & 63;
    if (node >= N_NODES) return;
    const float ep = 1.0f + eps_p[0];
    int b = ptr[node], e = ptr[node + 1];
    float4 acc = make_float4(0.f, 0.f, 0.f, 0.f);
    if (lane < 50) {
        float4 v = ((const float4*)(h + (size_t)node * 200))[lane];
        acc.x = ep * v.x; acc.y = ep * v.y; acc.z = ep * v.z; acc.w = ep * v.w;
    }
    for (int j = b; j < e; ++j) {
        int s = src[j];                        // wave-uniform
        if (lane < 50) {
            float4 v = ((const float4*)(h + (size_t)s * 200))[lane];   // coalesced 800B row
            acc.x += v.x; acc.y += v.y; acc.z += v.z; acc.w += v.w;
        }
    }
    if (lane < 50) ((float4*)(agg + (size_t)node * 200))[lane] = acc;
}

// ---------------- GEMM: out[N,200] = f(A[N,K] @ W[K,200] + bias) ----------------
// f = relu, then optional BN-eval. 32 rows per block, 256 threads, 8x4 register tile.
template <int K, bool BN>
__global__ __launch_bounds__(256) void gemm_kernel(
        const float* __restrict__ A, const float* __restrict__ W,
        const float* __restrict__ bias,
        const float* __restrict__ gamma, const float* __restrict__ beta,
        const float* __restrict__ mean, const float* __restrict__ var,
        float* __restrict__ out) {
    __shared__ __align__(16) float As[32][K];
    const int t = threadIdx.x;
    const size_t row0 = (size_t)blockIdx.x * 32;
    {
        const float4* Ag = (const float4*)(A + row0 * K);
        float4* As4 = (float4*)(&As[0][0]);
        const int n4 = 32 * K / 4;
        for (int i = t; i < n4; i += 256) As4[i] = Ag[i];
    }
    __syncthreads();
    const int tn = t & 63;   // column group: cols tn + 64*j
    const int tm = t >> 6;   // row group: rows tm*8 .. tm*8+7  (wave-uniform)
    float acc[8][4];
    #pragma unroll
    for (int r = 0; r < 8; ++r)
        #pragma unroll
        for (int j = 0; j < 4; ++j) acc[r][j] = 0.0f;

    for (int k = 0; k < K; k += 4) {
        float4 a4[8];
        #pragma unroll
        for (int r = 0; r < 8; ++r)
            a4[r] = *(const float4*)(&As[tm * 8 + r][k]);   // wave-broadcast ds_read_b128
        #pragma unroll
        for (int kk = 0; kk < 4; ++kk) {
            float w[4];
            #pragma unroll
            for (int j = 0; j < 4; ++j) {
                int c = tn + 64 * j;
                w[j] = (c < 200) ? W[(size_t)(k + kk) * 200 + c] : 0.0f;  // coalesced, L2-hot
            }
            #pragma unroll
            for (int r = 0; r < 8; ++r) {
                float a = ((const float*)(&a4[r]))[kk];
                #pragma unroll
                for (int j = 0; j < 4; ++j) acc[r][j] += a * w[j];
            }
        }
    }
    #pragma unroll
    for (int j = 0; j < 4; ++j) {
        int c = tn + 64 * j;
        if (c >= 200) continue;
        float bv = bias[c];
        float g0 = 0.f, bt = 0.f, mn = 0.f, inv = 0.f;
        if (BN) { g0 = gamma[c]; bt = beta[c]; mn = mean[c]; inv = rsqrtf(var[c] + 1e-5f); }
        #pragma unroll
        for (int r = 0; r < 8; ++r) {
            float v = acc[r][j] + bv;
            v = fmaxf(v, 0.0f);
            if (BN) v = (v - mn) * inv * g0 + bt;
            out[(row0 + tm * 8 + r) * 200 + c] = v;
        }
    }
}

// ---------------- Fused pooling (sum+max per graph) + FC + log_softmax ----------------
__device__ __forceinline__ int lower_bound_dev(const int* a, int n, int v) {
    int lo = 0, hi = n;
    while (lo < hi) { int mid = (lo + hi) >> 1; if (a[mid] < v) lo = mid + 1; else hi = mid; }
    return lo;
}

__global__ __launch_bounds__(256) void pool_fc_kernel(const float* __restrict__ h,
        const int* __restrict__ batch, const float* __restrict__ Wfc,
        const float* __restrict__ bfc, float* __restrict__ out) {
    int g = blockIdx.x;
    __shared__ int range[2];
    if (threadIdx.x == 0) range[0] = lower_bound_dev(batch, N_NODES, g);
    else if (threadIdx.x == 64) range[1] = lower_bound_dev(batch, N_NODES, g + 1);
    __syncthreads();
    int b = range[0], e = range[1];
    int d = threadIdx.x;
    float s = 0.0f, m = -3.0e38f;
    for (int n = b; n < e; ++n) {
        if (d < 200) {
            float v = h[(size_t)n * 200 + d];
            s += v;
            m = fmaxf(m, v);
        }
    }
    float c0 = 0.f, c1 = 0.f;
    if (d < 200) {
        c0 = s * Wfc[d * 2 + 0] + m * Wfc[(200 + d) * 2 + 0];
        c1 = s * Wfc[d * 2 + 1] + m * Wfc[(200 + d) * 2 + 1];
    }
    #pragma unroll
    for (int off = 32; off > 0; off >>= 1) {
        c0 += __shfl_down(c0, off, 64);
        c1 += __shfl_down(c1, off, 64);
    }
    __shared__ float r0[4], r1[4];
    int wid = threadIdx.x >> 6;
    if ((threadIdx.x & 63) == 0) { r0[wid] = c0; r1[wid] = c1; }
    __syncthreads();
    if (threadIdx.x == 0) {
        float l0 = r0[0] + r0[1] + r0[2] + r0[3] + bfc[0];
        float l1 = r1[0] + r1[1] + r1[2] + r1[3] + bfc[1];
        float mx = fmaxf(l0, l1);
        float lse = mx + logf(expf(l0 - mx) + expf(l1 - mx));
        out[g * 2 + 0] = l0 - lse;
        out[g * 2 + 1] = l1 - lse;
    }
}

// ---------------- launch ----------------
extern "C" void kernel_launch(void* const* d_in, const int* in_sizes, int n_in,
                              void* d_out, int out_size, void* d_ws, size_t ws_size,
                              hipStream_t stream) {
    const float* x    = (const float*)d_in[0];
    const int*   ei   = (const int*)d_in[1];
    const int*   batch= (const int*)d_in[2];
    const float* eps1 = (const float*)d_in[3];
    const float* W1a  = (const float*)d_in[4];
    const float* b1a  = (const float*)d_in[5];
    const float* W1b  = (const float*)d_in[6];
    const float* b1b  = (const float*)d_in[7];
    const float* bn1g = (const float*)d_in[8];
    const float* bn1b = (const float*)d_in[9];
    const float* bn1m = (const float*)d_in[10];
    const float* bn1v = (const float*)d_in[11];
    const float* eps2 = (const float*)d_in[12];
    const float* W2a  = (const float*)d_in[13];
    const float* b2a  = (const float*)d_in[14];
    const float* W2b  = (const float*)d_in[15];
    const float* b2b  = (const float*)d_in[16];
    const float* bn2g = (const float*)d_in[17];
    const float* bn2b = (const float*)d_in[18];
    const float* bn2m = (const float*)d_in[19];
    const float* bn2v = (const float*)d_in[20];
    const float* Wfc  = (const float*)d_in[21];
    const float* bfc  = (const float*)d_in[22];
    float* out = (float*)d_out;

    // workspace layout (256B aligned):
    // [0, 400128)            csr_ptr (N+1 ints)
    // [400128, 800256)       cursor  (N ints)
    // [800256, 7200256)      csr_src (E ints)
    // [7200256, +80MB)       bufA
    // [87200256, +80MB)      bufB     -> total 167,200,256 B
    char* ws = (char*)d_ws;
    int* csr_ptr = (int*)(ws + 0);
    int* cursor  = (int*)(ws + 400128);
    int* csr_src = (int*)(ws + 800256);
    float* bufA  = (float*)(ws + 7200256);
    float* bufB  = (float*)(ws + 7200256 + 80000000);

    float* agg1 = bufB;   // N x 64  (aliases bufB; dead before h1 is written)
    float* t1   = bufA;   // N x 200
    float* h1   = bufB;   // N x 200
    float* agg2 = bufA;   // N x 200
    float* t2   = bufB;   // N x 200
    float* h2   = bufA;   // N x 200

    hipMemsetAsync(cursor, 0, N_NODES * sizeof(int), stream);
    hist_kernel<<<(N_EDGES + 255) / 256, 256, 0, stream>>>(ei, cursor);
    scan_kernel<<<1, 1024, 0, stream>>>(cursor, csr_ptr);
    fill_kernel<<<(N_EDGES + 255) / 256, 256, 0, stream>>>(ei, cursor, csr_src);

    agg1_kernel<<<N_NODES / 4, 256, 0, stream>>>(x, csr_ptr, csr_src, eps1, agg1);
    gemm_kernel<64,  false><<<N_NODES / 32, 256, 0, stream>>>(agg1, W1a, b1a,
            nullptr, nullptr, nullptr, nullptr, t1);
    gemm_kernel<200, true ><<<N_NODES / 32, 256, 0, stream>>>(t1, W1b, b1b,
            bn1g, bn1b, bn1m, bn1v, h1);

    agg2_kernel<<<N_NODES / 4, 256, 0, stream>>>(h1, csr_ptr, csr_src, eps2, agg2);
    gemm_kernel<200, false><<<N_NODES / 32, 256, 0, stream>>>(agg2, W2a, b2a,
            nullptr, nullptr, nullptr, nullptr, t2);
    gemm_kernel<200, true ><<<N_NODES / 32, 256, 0, stream>>>(t2, W2b, b2b,
            bn2g, bn2b, bn2m, bn2v, h2);

    pool_fc_kernel<<<N_GRAPHS, 256, 0, stream>>>(h2, batch, Wfc, bfc, out);
}

// Round 2
// 1240.570 us; speedup vs baseline: 1.1283x; 1.1283x over previous
//
#include <hip/hip_runtime.h>
#include <hip/hip_bf16.h>
#include <math.h>

#define N_NODES 100000
#define N_EDGES 1600000
#define F_IN 64
#define H_DIM 200
#define N_GRAPHS 512
#define NB_SCAN 98   // ceil(100000 / 1024)

// ---------------- CSR build: histogram by dst ----------------
__global__ void hist_kernel(const int* __restrict__ ei, int* __restrict__ cnt) {
    int i = blockIdx.x * blockDim.x + threadIdx.x;
    if (i < N_EDGES) atomicAdd(&cnt[ei[N_EDGES + i]], 1);
}

// ---- hierarchical scan: S1 per-block sums (1024 nodes/block) ----
__global__ __launch_bounds__(256) void scan_part(const int* __restrict__ deg,
                                                 int* __restrict__ bsums) {
    int b = blockIdx.x, t = threadIdx.x;
    int i0 = b * 1024 + t * 4;
    int s = 0;
    #pragma unroll
    for (int k = 0; k < 4; ++k) { int i = i0 + k; if (i < N_NODES) s += deg[i]; }
    #pragma unroll
    for (int off = 32; off > 0; off >>= 1) s += __shfl_down(s, off, 64);
    __shared__ int wsum[4];
    if ((t & 63) == 0) wsum[t >> 6] = s;
    __syncthreads();
    if (t == 0) bsums[b] = wsum[0] + wsum[1] + wsum[2] + wsum[3];
}

// ---- S2: single small block scans the 98 block totals (exclusive) ----
__global__ void scan_tops(int* __restrict__ bsums, int* __restrict__ ptr) {
    __shared__ int sh[128];
    int t = threadIdx.x;
    int v = (t < NB_SCAN) ? bsums[t] : 0;
    sh[t] = v;
    __syncthreads();
    for (int off = 1; off < 128; off <<= 1) {
        int a = sh[t];
        int add = (t >= off) ? sh[t - off] : 0;
        __syncthreads();
        sh[t] = a + add;
        __syncthreads();
    }
    if (t < NB_SCAN) bsums[t] = sh[t] - v;     // exclusive prefix
    if (t == 127) ptr[N_NODES] = sh[127];      // total edge count
}

// ---- S3: finalize per-node offsets; cursor[i] = ptr[i] for the fill pass ----
__global__ __launch_bounds__(256) void scan_fin(int* __restrict__ deg_cursor,
                                                const int* __restrict__ bsums,
                                                int* __restrict__ ptr) {
    int b = blockIdx.x, t = threadIdx.x;
    int i0 = b * 1024 + t * 4;
    int d[4]; int s = 0;
    #pragma unroll
    for (int k = 0; k < 4; ++k) {
        int i = i0 + k;
        d[k] = (i < N_NODES) ? deg_cursor[i] : 0;
        s += d[k];
    }
    __shared__ int sh[256];
    sh[t] = s;
    __syncthreads();
    for (int off = 1; off < 256; off <<= 1) {
        int a = sh[t];
        int add = (t >= off) ? sh[t - off] : 0;
        __syncthreads();
        sh[t] = a + add;
        __syncthreads();
    }
    int run = bsums[b] + sh[t] - s;
    #pragma unroll
    for (int k = 0; k < 4; ++k) {
        int i = i0 + k;
        if (i < N_NODES) { ptr[i] = run; deg_cursor[i] = run; run += d[k]; }
    }
}

__global__ void fill_kernel(const int* __restrict__ ei, int* __restrict__ cursor,
                            int* __restrict__ csr_src) {
    int i = blockIdx.x * blockDim.x + threadIdx.x;
    if (i < N_EDGES) {
        int s = ei[i];
        int d = ei[N_EDGES + i];
        int p = atomicAdd(&cursor[d], 1);
        csr_src[p] = s;
    }
}

// ---------------- Fused GIN layer: gather + MLP(GEMM,relu,GEMM,relu) + BN ----------------
// One block = 32 nodes. Phase A: CSR gather of (1+eps)*x + sum(neighbors) into LDS.
// Phase B: t = relu(S[:, :K1] @ Wa + ba)  (8x4 register tile per thread).
// Phase C: t written back into the same LDS tile.
// Phase D: out = BN(relu(t @ Wb + bb)).
template <int K1, bool FIRST>
__global__ __launch_bounds__(256) void fused_gin(
        const float* __restrict__ X,
        const int* __restrict__ ptr, const int* __restrict__ srcl,
        const float* __restrict__ eps_p,
        const float* __restrict__ Wa, const float* __restrict__ ba,
        const float* __restrict__ Wb, const float* __restrict__ bb,
        const float* __restrict__ gamma, const float* __restrict__ beta,
        const float* __restrict__ mean, const float* __restrict__ var,
        float* __restrict__ out) {
    __shared__ __align__(16) float S[32][200];   // 25.6 KB -> 6 blocks/CU
    const int t = threadIdx.x;
    const int lane = t & 63;
    const int wid = t >> 6;
    const int node0 = blockIdx.x * 32;
    const float ep = 1.0f + eps_p[0];

    // ---- Phase A: gather (one wave handles 8 rows) ----
    if (FIRST) {
        for (int r = 0; r < 8; ++r) {
            int node = node0 + wid * 8 + r;
            int b = ptr[node], e = ptr[node + 1];
            float acc = ep * X[(size_t)node * 64 + lane];
            for (int j = b; j < e; ++j)
                acc += X[(size_t)srcl[j] * 64 + lane];   // coalesced 256B row
            S[wid * 8 + r][lane] = acc;
        }
    } else {
        for (int r = 0; r < 8; ++r) {
            int node = node0 + wid * 8 + r;
            int b = ptr[node], e = ptr[node + 1];
            float4 acc = make_float4(0.f, 0.f, 0.f, 0.f);
            if (lane < 50) {
                float4 v = *(const float4*)(X + (size_t)node * 200 + 4 * lane);
                acc.x = ep * v.x; acc.y = ep * v.y; acc.z = ep * v.z; acc.w = ep * v.w;
            }
            for (int j = b; j < e; ++j) {
                int s = srcl[j];                           // wave-uniform
                if (lane < 50) {
                    float4 v = *(const float4*)(X + (size_t)s * 200 + 4 * lane);
                    acc.x += v.x; acc.y += v.y; acc.z += v.z; acc.w += v.w;
                }
            }
            if (lane < 50) *(float4*)(&S[wid * 8 + r][4 * lane]) = acc;
        }
    }
    __syncthreads();

    const int tn = lane;     // cols tn + 64*j, j=0..3
    const int tm = wid;      // rows tm*8 .. tm*8+7 (wave-uniform)

    // ---- Phase B: GEMM1 over K1 ----
    float acc1[8][4];
    #pragma unroll
    for (int r = 0; r < 8; ++r)
        #pragma unroll
        for (int j = 0; j < 4; ++j) acc1[r][j] = 0.0f;

    for (int k = 0; k < K1; k += 4) {
        float4 a4[8];
        #pragma unroll
        for (int r = 0; r < 8; ++r)
            a4[r] = *(const float4*)(&S[tm * 8 + r][k]);    // wave-broadcast ds_read_b128
        #pragma unroll
        for (int kk = 0; kk < 4; ++kk) {
            float w[4];
            #pragma unroll
            for (int j = 0; j < 4; ++j) {
                int c = tn + 64 * j;
                w[j] = (c < 200) ? Wa[(size_t)(k + kk) * 200 + c] : 0.0f;
            }
            #pragma unroll
            for (int r = 0; r < 8; ++r) {
                float a = ((const float*)(&a4[r]))[kk];
                #pragma unroll
                for (int j = 0; j < 4; ++j) acc1[r][j] += a * w[j];
            }
        }
    }
    __syncthreads();   // everyone done reading S

    // ---- Phase C: write t = relu(acc1 + ba) back into S ----
    #pragma unroll
    for (int j = 0; j < 4; ++j) {
        int c = tn + 64 * j;
        if (c < 200) {
            float bv = ba[c];
            #pragma unroll
            for (int r = 0; r < 8; ++r)
                S[tm * 8 + r][c] = fmaxf(acc1[r][j] + bv, 0.0f);
        }
    }
    __syncthreads();

    // ---- Phase D: GEMM2 over K=200 + relu + BN ----
    float acc2[8][4];
    #pragma unroll
    for (int r = 0; r < 8; ++r)
        #pragma unroll
        for (int j = 0; j < 4; ++j) acc2[r][j] = 0.0f;

    for (int k = 0; k < 200; k += 4) {
        float4 a4[8];
        #pragma unroll
        for (int r = 0; r < 8; ++r)
            a4[r] = *(const float4*)(&S[tm * 8 + r][k]);
        #pragma unroll
        for (int kk = 0; kk < 4; ++kk) {
            float w[4];
            #pragma unroll
            for (int j = 0; j < 4; ++j) {
                int c = tn + 64 * j;
                w[j] = (c < 200) ? Wb[(size_t)(k + kk) * 200 + c] : 0.0f;
            }
            #pragma unroll
            for (int r = 0; r < 8; ++r) {
                float a = ((const float*)(&a4[r]))[kk];
                #pragma unroll
                for (int j = 0; j < 4; ++j) acc2[r][j] += a * w[j];
            }
        }
    }

    #pragma unroll
    for (int j = 0; j < 4; ++j) {
        int c = tn + 64 * j;
        if (c >= 200) continue;
        float bv = bb[c];
        float g0 = gamma[c], bt = beta[c], mn = mean[c];
        float inv = rsqrtf(var[c] + 1e-5f);
        #pragma unroll
        for (int r = 0; r < 8; ++r) {
            float v = fmaxf(acc2[r][j] + bv, 0.0f);
            v = (v - mn) * inv * g0 + bt;
            out[(size_t)(node0 + tm * 8 + r) * 200 + c] = v;
        }
    }
}

// ---------------- Fused pooling (sum+max per graph) + FC + log_softmax ----------------
__device__ __forceinline__ int lower_bound_dev(const int* a, int n, int v) {
    int lo = 0, hi = n;
    while (lo < hi) { int mid = (lo + hi) >> 1; if (a[mid] < v) lo = mid + 1; else hi = mid; }
    return lo;
}

__global__ __launch_bounds__(256) void pool_fc_kernel(const float* __restrict__ h,
        const int* __restrict__ batch, const float* __restrict__ Wfc,
        const float* __restrict__ bfc, float* __restrict__ out) {
    int g = blockIdx.x;
    __shared__ int range[2];
    if (threadIdx.x == 0) range[0] = lower_bound_dev(batch, N_NODES, g);
    else if (threadIdx.x == 64) range[1] = lower_bound_dev(batch, N_NODES, g + 1);
    __syncthreads();
    int b = range[0], e = range[1];
    int d = threadIdx.x;
    float s = 0.0f, m = -3.0e38f;
    for (int n = b; n < e; ++n) {
        if (d < 200) {
            float v = h[(size_t)n * 200 + d];
            s += v;
            m = fmaxf(m, v);
        }
    }
    float c0 = 0.f, c1 = 0.f;
    if (d < 200) {
        c0 = s * Wfc[d * 2 + 0] + m * Wfc[(200 + d) * 2 + 0];
        c1 = s * Wfc[d * 2 + 1] + m * Wfc[(200 + d) * 2 + 1];
    }
    #pragma unroll
    for (int off = 32; off > 0; off >>= 1) {
        c0 += __shfl_down(c0, off, 64);
        c1 += __shfl_down(c1, off, 64);
    }
    __shared__ float r0[4], r1[4];
    int wid = threadIdx.x >> 6;
    if ((threadIdx.x & 63) == 0) { r0[wid] = c0; r1[wid] = c1; }
    __syncthreads();
    if (threadIdx.x == 0) {
        float l0 = r0[0] + r0[1] + r0[2] + r0[3] + bfc[0];
        float l1 = r1[0] + r1[1] + r1[2] + r1[3] + bfc[1];
        float mx = fmaxf(l0, l1);
        float lse = mx + logf(expf(l0 - mx) + expf(l1 - mx));
        out[g * 2 + 0] = l0 - lse;
        out[g * 2 + 1] = l1 - lse;
    }
}

// ---------------- launch ----------------
extern "C" void kernel_launch(void* const* d_in, const int* in_sizes, int n_in,
                              void* d_out, int out_size, void* d_ws, size_t ws_size,
                              hipStream_t stream) {
    const float* x    = (const float*)d_in[0];
    const int*   ei   = (const int*)d_in[1];
    const int*   batch= (const int*)d_in[2];
    const float* eps1 = (const float*)d_in[3];
    const float* W1a  = (const float*)d_in[4];
    const float* b1a  = (const float*)d_in[5];
    const float* W1b  = (const float*)d_in[6];
    const float* b1b  = (const float*)d_in[7];
    const float* bn1g = (const float*)d_in[8];
    const float* bn1b = (const float*)d_in[9];
    const float* bn1m = (const float*)d_in[10];
    const float* bn1v = (const float*)d_in[11];
    const float* eps2 = (const float*)d_in[12];
    const float* W2a  = (const float*)d_in[13];
    const float* b2a  = (const float*)d_in[14];
    const float* W2b  = (const float*)d_in[15];
    const float* b2b  = (const float*)d_in[16];
    const float* bn2g = (const float*)d_in[17];
    const float* bn2b = (const float*)d_in[18];
    const float* bn2m = (const float*)d_in[19];
    const float* bn2v = (const float*)d_in[20];
    const float* Wfc  = (const float*)d_in[21];
    const float* bfc  = (const float*)d_in[22];
    float* out = (float*)d_out;

    // workspace layout (same 167,200,256 B footprint as the passing round):
    // [0, 400128)            csr_ptr (N+1 ints)
    // [400128, 800256)       cursor  (N ints; holds degrees, then offsets)
    // [800256, 7200256)      csr_src (E ints)
    // [7200256, +80MB)       h1
    // [87200256, +80MB)      h2
    // bsums (98 ints) aliases the h1 region: only live during the scan.
    char* ws = (char*)d_ws;
    int* csr_ptr = (int*)(ws + 0);
    int* cursor  = (int*)(ws + 400128);
    int* csr_src = (int*)(ws + 800256);
    float* h1    = (float*)(ws + 7200256);
    float* h2    = (float*)(ws + 87200256);
    int* bsums   = (int*)(ws + 7200256);   // alias: dead before h1 is written

    hipMemsetAsync(cursor, 0, N_NODES * sizeof(int), stream);
    hist_kernel<<<(N_EDGES + 255) / 256, 256, 0, stream>>>(ei, cursor);
    scan_part<<<NB_SCAN, 256, 0, stream>>>(cursor, bsums);
    scan_tops<<<1, 128, 0, stream>>>(bsums, csr_ptr);
    scan_fin<<<NB_SCAN, 256, 0, stream>>>(cursor, bsums, csr_ptr);
    fill_kernel<<<(N_EDGES + 255) / 256, 256, 0, stream>>>(ei, cursor, csr_src);

    fused_gin<64, true><<<N_NODES / 32, 256, 0, stream>>>(x, csr_ptr, csr_src,
            eps1, W1a, b1a, W1b, b1b, bn1g, bn1b, bn1m, bn1v, h1);
    fused_gin<200, false><<<N_NODES / 32, 256, 0, stream>>>(h1, csr_ptr, csr_src,
            eps2, W2a, b2a, W2b, b2b, bn2g, bn2b, bn2m, bn2v, h2);

    pool_fc_kernel<<<N_GRAPHS, 256, 0, stream>>>(h2, batch, Wfc, bfc, out);
}

// Round 3
// 933.928 us; speedup vs baseline: 1.4987x; 1.3283x over previous
//
#include <hip/hip_runtime.h>
#include <hip/hip_bf16.h>
#include <math.h>

#define N_NODES 100000
#define N_EDGES 1600000
#define F_IN 64
#define H_DIM 200
#define N_GRAPHS 512
#define NB_SCAN 98   // ceil(100000 / 1024)

// ---------------- CSR build: histogram by dst ----------------
__global__ void hist_kernel(const int* __restrict__ ei, int* __restrict__ cnt) {
    int i = blockIdx.x * blockDim.x + threadIdx.x;
    if (i < N_EDGES) atomicAdd(&cnt[ei[N_EDGES + i]], 1);
}

// ---- hierarchical scan: S1 per-block sums (1024 nodes/block) ----
__global__ __launch_bounds__(256) void scan_part(const int* __restrict__ deg,
                                                 int* __restrict__ bsums) {
    int b = blockIdx.x, t = threadIdx.x;
    int i0 = b * 1024 + t * 4;
    int s = 0;
    #pragma unroll
    for (int k = 0; k < 4; ++k) { int i = i0 + k; if (i < N_NODES) s += deg[i]; }
    #pragma unroll
    for (int off = 32; off > 0; off >>= 1) s += __shfl_down(s, off, 64);
    __shared__ int wsum[4];
    if ((t & 63) == 0) wsum[t >> 6] = s;
    __syncthreads();
    if (t == 0) bsums[b] = wsum[0] + wsum[1] + wsum[2] + wsum[3];
}

// ---- S2: single small block scans the 98 block totals (exclusive) ----
__global__ void scan_tops(int* __restrict__ bsums, int* __restrict__ ptr) {
    __shared__ int sh[128];
    int t = threadIdx.x;
    int v = (t < NB_SCAN) ? bsums[t] : 0;
    sh[t] = v;
    __syncthreads();
    for (int off = 1; off < 128; off <<= 1) {
        int a = sh[t];
        int add = (t >= off) ? sh[t - off] : 0;
        __syncthreads();
        sh[t] = a + add;
        __syncthreads();
    }
    if (t < NB_SCAN) bsums[t] = sh[t] - v;     // exclusive prefix
    if (t == 127) ptr[N_NODES] = sh[127];      // total edge count
}

// ---- S3: finalize per-node offsets; cursor[i] = ptr[i] for the fill pass ----
__global__ __launch_bounds__(256) void scan_fin(int* __restrict__ deg_cursor,
                                                const int* __restrict__ bsums,
                                                int* __restrict__ ptr) {
    int b = blockIdx.x, t = threadIdx.x;
    int i0 = b * 1024 + t * 4;
    int d[4]; int s = 0;
    #pragma unroll
    for (int k = 0; k < 4; ++k) {
        int i = i0 + k;
        d[k] = (i < N_NODES) ? deg_cursor[i] : 0;
        s += d[k];
    }
    __shared__ int sh[256];
    sh[t] = s;
    __syncthreads();
    for (int off = 1; off < 256; off <<= 1) {
        int a = sh[t];
        int add = (t >= off) ? sh[t - off] : 0;
        __syncthreads();
        sh[t] = a + add;
        __syncthreads();
    }
    int run = bsums[b] + sh[t] - s;
    #pragma unroll
    for (int k = 0; k < 4; ++k) {
        int i = i0 + k;
        if (i < N_NODES) { ptr[i] = run; deg_cursor[i] = run; run += d[k]; }
    }
}

__global__ void fill_kernel(const int* __restrict__ ei, int* __restrict__ cursor,
                            int* __restrict__ csr_src) {
    int i = blockIdx.x * blockDim.x + threadIdx.x;
    if (i < N_EDGES) {
        int s = ei[i];
        int d = ei[N_EDGES + i];
        int p = atomicAdd(&cursor[d], 1);
        csr_src[p] = s;
    }
}

// bf16x4 (uint2) -> float4
__device__ __forceinline__ float4 bf4_to_f4(uint2 u) {
    float4 r;
    r.x = __uint_as_float(u.x << 16);
    r.y = __uint_as_float(u.x & 0xffff0000u);
    r.z = __uint_as_float(u.y << 16);
    r.w = __uint_as_float(u.y & 0xffff0000u);
    return r;
}

// ---------------- GIN layer 1: gather fp32 x (8-deep ILP) + MLP + BN -> bf16 out ----------------
__global__ __launch_bounds__(256) void gin_layer1(
        const float* __restrict__ X,
        const int* __restrict__ ptr, const int* __restrict__ srcl,
        const float* __restrict__ eps_p,
        const float* __restrict__ Wa, const float* __restrict__ ba,
        const float* __restrict__ Wb, const float* __restrict__ bb,
        const float* __restrict__ gamma, const float* __restrict__ beta,
        const float* __restrict__ mean, const float* __restrict__ var,
        __hip_bfloat16* __restrict__ out) {
    __shared__ __align__(16) float S[32][200];   // 25.6 KB
    const int t = threadIdx.x;
    const int lane = t & 63;
    const int wid = t >> 6;
    const int node0 = blockIdx.x * 32;
    const float ep = 1.0f + eps_p[0];

    // ---- gather: one wave per row, 8 loads in flight ----
    for (int r = 0; r < 8; ++r) {
        int node = node0 + wid * 8 + r;
        int b = ptr[node], e = ptr[node + 1];
        float a0 = ep * X[(size_t)node * 64 + lane];
        float a1 = 0.f, a2 = 0.f, a3 = 0.f, a4 = 0.f, a5 = 0.f, a6 = 0.f, a7 = 0.f;
        int j = b;
        for (; j + 8 <= e; j += 8) {
            int s0 = srcl[j+0], s1 = srcl[j+1], s2 = srcl[j+2], s3 = srcl[j+3];
            int s4 = srcl[j+4], s5 = srcl[j+5], s6 = srcl[j+6], s7 = srcl[j+7];
            a0 += X[(size_t)s0 * 64 + lane];
            a1 += X[(size_t)s1 * 64 + lane];
            a2 += X[(size_t)s2 * 64 + lane];
            a3 += X[(size_t)s3 * 64 + lane];
            a4 += X[(size_t)s4 * 64 + lane];
            a5 += X[(size_t)s5 * 64 + lane];
            a6 += X[(size_t)s6 * 64 + lane];
            a7 += X[(size_t)s7 * 64 + lane];
        }
        if (j + 4 <= e) {
            int s0 = srcl[j+0], s1 = srcl[j+1], s2 = srcl[j+2], s3 = srcl[j+3];
            a0 += X[(size_t)s0 * 64 + lane];
            a1 += X[(size_t)s1 * 64 + lane];
            a2 += X[(size_t)s2 * 64 + lane];
            a3 += X[(size_t)s3 * 64 + lane];
            j += 4;
        }
        for (; j < e; ++j) a0 += X[(size_t)srcl[j] * 64 + lane];
        S[wid * 8 + r][lane] = ((a0 + a1) + (a2 + a3)) + ((a4 + a5) + (a6 + a7));
    }
    __syncthreads();

    const int tn = lane;
    const int tm = wid;

    // ---- GEMM1 over K=64 ----
    float acc1[8][4];
    #pragma unroll
    for (int r = 0; r < 8; ++r)
        #pragma unroll
        for (int j = 0; j < 4; ++j) acc1[r][j] = 0.0f;

    for (int k = 0; k < 64; k += 4) {
        float4 a4[8];
        #pragma unroll
        for (int r = 0; r < 8; ++r)
            a4[r] = *(const float4*)(&S[tm * 8 + r][k]);
        #pragma unroll
        for (int kk = 0; kk < 4; ++kk) {
            float w[4];
            #pragma unroll
            for (int j = 0; j < 4; ++j) {
                int c = tn + 64 * j;
                w[j] = (c < 200) ? Wa[(size_t)(k + kk) * 200 + c] : 0.0f;
            }
            #pragma unroll
            for (int r = 0; r < 8; ++r) {
                float a = ((const float*)(&a4[r]))[kk];
                #pragma unroll
                for (int j = 0; j < 4; ++j) acc1[r][j] += a * w[j];
            }
        }
    }
    __syncthreads();

    // ---- t = relu(acc1 + ba) back into S ----
    #pragma unroll
    for (int j = 0; j < 4; ++j) {
        int c = tn + 64 * j;
        if (c < 200) {
            float bv = ba[c];
            #pragma unroll
            for (int r = 0; r < 8; ++r)
                S[tm * 8 + r][c] = fmaxf(acc1[r][j] + bv, 0.0f);
        }
    }
    __syncthreads();

    // ---- GEMM2 over K=200 + relu + BN -> bf16 ----
    float acc2[8][4];
    #pragma unroll
    for (int r = 0; r < 8; ++r)
        #pragma unroll
        for (int j = 0; j < 4; ++j) acc2[r][j] = 0.0f;

    for (int k = 0; k < 200; k += 4) {
        float4 a4[8];
        #pragma unroll
        for (int r = 0; r < 8; ++r)
            a4[r] = *(const float4*)(&S[tm * 8 + r][k]);
        #pragma unroll
        for (int kk = 0; kk < 4; ++kk) {
            float w[4];
            #pragma unroll
            for (int j = 0; j < 4; ++j) {
                int c = tn + 64 * j;
                w[j] = (c < 200) ? Wb[(size_t)(k + kk) * 200 + c] : 0.0f;
            }
            #pragma unroll
            for (int r = 0; r < 8; ++r) {
                float a = ((const float*)(&a4[r]))[kk];
                #pragma unroll
                for (int j = 0; j < 4; ++j) acc2[r][j] += a * w[j];
            }
        }
    }

    #pragma unroll
    for (int j = 0; j < 4; ++j) {
        int c = tn + 64 * j;
        if (c >= 200) continue;
        float bv = bb[c];
        float g0 = gamma[c], bt = beta[c], mn = mean[c];
        float inv = rsqrtf(var[c] + 1e-5f);
        #pragma unroll
        for (int r = 0; r < 8; ++r) {
            float v = fmaxf(acc2[r][j] + bv, 0.0f);
            v = (v - mn) * inv * g0 + bt;
            out[(size_t)(node0 + tm * 8 + r) * 200 + c] = __float2bfloat16(v);
        }
    }
}

// ---------------- GIN layer 2: gather bf16 h1 (4-deep ILP) + MLP + BN -> fp32 out ----------------
__global__ __launch_bounds__(256) void gin_layer2(
        const __hip_bfloat16* __restrict__ Hb,
        const int* __restrict__ ptr, const int* __restrict__ srcl,
        const float* __restrict__ eps_p,
        const float* __restrict__ Wa, const float* __restrict__ ba,
        const float* __restrict__ Wb, const float* __restrict__ bb,
        const float* __restrict__ gamma, const float* __restrict__ beta,
        const float* __restrict__ mean, const float* __restrict__ var,
        float* __restrict__ out) {
    __shared__ __align__(16) float S[32][200];
    const int t = threadIdx.x;
    const int lane = t & 63;
    const int wid = t >> 6;
    const int node0 = blockIdx.x * 32;
    const float ep = 1.0f + eps_p[0];
    const uint2* H2 = (const uint2*)Hb;     // 50 uint2 (4 bf16 each) per row

    // ---- gather: one wave per row, 50 active lanes x 8B, 4 rows in flight ----
    for (int r = 0; r < 8; ++r) {
        int node = node0 + wid * 8 + r;
        int b = ptr[node], e = ptr[node + 1];
        if (lane < 50) {
            uint2 us = H2[(size_t)node * 50 + lane];
            float4 fs = bf4_to_f4(us);
            float4 a0 = make_float4(ep * fs.x, ep * fs.y, ep * fs.z, ep * fs.w);
            float4 a1 = make_float4(0.f, 0.f, 0.f, 0.f);
            float4 a2 = make_float4(0.f, 0.f, 0.f, 0.f);
            float4 a3 = make_float4(0.f, 0.f, 0.f, 0.f);
            int j = b;
            for (; j + 4 <= e; j += 4) {
                int s0 = srcl[j+0], s1 = srcl[j+1], s2 = srcl[j+2], s3 = srcl[j+3];
                uint2 u0 = H2[(size_t)s0 * 50 + lane];
                uint2 u1 = H2[(size_t)s1 * 50 + lane];
                uint2 u2 = H2[(size_t)s2 * 50 + lane];
                uint2 u3 = H2[(size_t)s3 * 50 + lane];
                float4 f0 = bf4_to_f4(u0), f1 = bf4_to_f4(u1);
                float4 f2 = bf4_to_f4(u2), f3 = bf4_to_f4(u3);
                a0.x += f0.x; a0.y += f0.y; a0.z += f0.z; a0.w += f0.w;
                a1.x += f1.x; a1.y += f1.y; a1.z += f1.z; a1.w += f1.w;
                a2.x += f2.x; a2.y += f2.y; a2.z += f2.z; a2.w += f2.w;
                a3.x += f3.x; a3.y += f3.y; a3.z += f3.z; a3.w += f3.w;
            }
            for (; j < e; ++j) {
                uint2 u0 = H2[(size_t)srcl[j] * 50 + lane];
                float4 f0 = bf4_to_f4(u0);
                a0.x += f0.x; a0.y += f0.y; a0.z += f0.z; a0.w += f0.w;
            }
            float4 acc;
            acc.x = (a0.x + a1.x) + (a2.x + a3.x);
            acc.y = (a0.y + a1.y) + (a2.y + a3.y);
            acc.z = (a0.z + a1.z) + (a2.z + a3.z);
            acc.w = (a0.w + a1.w) + (a2.w + a3.w);
            *(float4*)(&S[wid * 8 + r][4 * lane]) = acc;
        }
    }
    __syncthreads();

    const int tn = lane;
    const int tm = wid;

    // ---- GEMM1 over K=200 ----
    float acc1[8][4];
    #pragma unroll
    for (int r = 0; r < 8; ++r)
        #pragma unroll
        for (int j = 0; j < 4; ++j) acc1[r][j] = 0.0f;

    for (int k = 0; k < 200; k += 4) {
        float4 a4[8];
        #pragma unroll
        for (int r = 0; r < 8; ++r)
            a4[r] = *(const float4*)(&S[tm * 8 + r][k]);
        #pragma unroll
        for (int kk = 0; kk < 4; ++kk) {
            float w[4];
            #pragma unroll
            for (int j = 0; j < 4; ++j) {
                int c = tn + 64 * j;
                w[j] = (c < 200) ? Wa[(size_t)(k + kk) * 200 + c] : 0.0f;
            }
            #pragma unroll
            for (int r = 0; r < 8; ++r) {
                float a = ((const float*)(&a4[r]))[kk];
                #pragma unroll
                for (int j = 0; j < 4; ++j) acc1[r][j] += a * w[j];
            }
        }
    }
    __syncthreads();

    // ---- t = relu(acc1 + ba) back into S ----
    #pragma unroll
    for (int j = 0; j < 4; ++j) {
        int c = tn + 64 * j;
        if (c < 200) {
            float bv = ba[c];
            #pragma unroll
            for (int r = 0; r < 8; ++r)
                S[tm * 8 + r][c] = fmaxf(acc1[r][j] + bv, 0.0f);
        }
    }
    __syncthreads();

    // ---- GEMM2 over K=200 + relu + BN -> fp32 ----
    float acc2[8][4];
    #pragma unroll
    for (int r = 0; r < 8; ++r)
        #pragma unroll
        for (int j = 0; j < 4; ++j) acc2[r][j] = 0.0f;

    for (int k = 0; k < 200; k += 4) {
        float4 a4[8];
        #pragma unroll
        for (int r = 0; r < 8; ++r)
            a4[r] = *(const float4*)(&S[tm * 8 + r][k]);
        #pragma unroll
        for (int kk = 0; kk < 4; ++kk) {
            float w[4];
            #pragma unroll
            for (int j = 0; j < 4; ++j) {
                int c = tn + 64 * j;
                w[j] = (c < 200) ? Wb[(size_t)(k + kk) * 200 + c] : 0.0f;
            }
            #pragma unroll
            for (int r = 0; r < 8; ++r) {
                float a = ((const float*)(&a4[r]))[kk];
                #pragma unroll
                for (int j = 0; j < 4; ++j) acc2[r][j] += a * w[j];
            }
        }
    }

    #pragma unroll
    for (int j = 0; j < 4; ++j) {
        int c = tn + 64 * j;
        if (c >= 200) continue;
        float bv = bb[c];
        float g0 = gamma[c], bt = beta[c], mn = mean[c];
        float inv = rsqrtf(var[c] + 1e-5f);
        #pragma unroll
        for (int r = 0; r < 8; ++r) {
            float v = fmaxf(acc2[r][j] + bv, 0.0f);
            v = (v - mn) * inv * g0 + bt;
            out[(size_t)(node0 + tm * 8 + r) * 200 + c] = v;
        }
    }
}

// ---------------- Fused pooling (sum+max per graph) + FC + log_softmax ----------------
__device__ __forceinline__ int lower_bound_dev(const int* a, int n, int v) {
    int lo = 0, hi = n;
    while (lo < hi) { int mid = (lo + hi) >> 1; if (a[mid] < v) lo = mid + 1; else hi = mid; }
    return lo;
}

__global__ __launch_bounds__(256) void pool_fc_kernel(const float* __restrict__ h,
        const int* __restrict__ batch, const float* __restrict__ Wfc,
        const float* __restrict__ bfc, float* __restrict__ out) {
    int g = blockIdx.x;
    __shared__ int range[2];
    if (threadIdx.x == 0) range[0] = lower_bound_dev(batch, N_NODES, g);
    else if (threadIdx.x == 64) range[1] = lower_bound_dev(batch, N_NODES, g + 1);
    __syncthreads();
    int b = range[0], e = range[1];
    int d = threadIdx.x;
    float s = 0.0f, m = -3.0e38f;
    for (int n = b; n < e; ++n) {
        if (d < 200) {
            float v = h[(size_t)n * 200 + d];
            s += v;
            m = fmaxf(m, v);
        }
    }
    float c0 = 0.f, c1 = 0.f;
    if (d < 200) {
        c0 = s * Wfc[d * 2 + 0] + m * Wfc[(200 + d) * 2 + 0];
        c1 = s * Wfc[d * 2 + 1] + m * Wfc[(200 + d) * 2 + 1];
    }
    #pragma unroll
    for (int off = 32; off > 0; off >>= 1) {
        c0 += __shfl_down(c0, off, 64);
        c1 += __shfl_down(c1, off, 64);
    }
    __shared__ float r0[4], r1[4];
    int wid = threadIdx.x >> 6;
    if ((threadIdx.x & 63) == 0) { r0[wid] = c0; r1[wid] = c1; }
    __syncthreads();
    if (threadIdx.x == 0) {
        float l0 = r0[0] + r0[1] + r0[2] + r0[3] + bfc[0];
        float l1 = r1[0] + r1[1] + r1[2] + r1[3] + bfc[1];
        float mx = fmaxf(l0, l1);
        float lse = mx + logf(expf(l0 - mx) + expf(l1 - mx));
        out[g * 2 + 0] = l0 - lse;
        out[g * 2 + 1] = l1 - lse;
    }
}

// ---------------- launch ----------------
extern "C" void kernel_launch(void* const* d_in, const int* in_sizes, int n_in,
                              void* d_out, int out_size, void* d_ws, size_t ws_size,
                              hipStream_t stream) {
    const float* x    = (const float*)d_in[0];
    const int*   ei   = (const int*)d_in[1];
    const int*   batch= (const int*)d_in[2];
    const float* eps1 = (const float*)d_in[3];
    const float* W1a  = (const float*)d_in[4];
    const float* b1a  = (const float*)d_in[5];
    const float* W1b  = (const float*)d_in[6];
    const float* b1b  = (const float*)d_in[7];
    const float* bn1g = (const float*)d_in[8];
    const float* bn1b = (const float*)d_in[9];
    const float* bn1m = (const float*)d_in[10];
    const float* bn1v = (const float*)d_in[11];
    const float* eps2 = (const float*)d_in[12];
    const float* W2a  = (const float*)d_in[13];
    const float* b2a  = (const float*)d_in[14];
    const float* W2b  = (const float*)d_in[15];
    const float* b2b  = (const float*)d_in[16];
    const float* bn2g = (const float*)d_in[17];
    const float* bn2b = (const float*)d_in[18];
    const float* bn2m = (const float*)d_in[19];
    const float* bn2v = (const float*)d_in[20];
    const float* Wfc  = (const float*)d_in[21];
    const float* bfc  = (const float*)d_in[22];
    float* out = (float*)d_out;

    // workspace layout (127,200,256 B total; well under the proven 167 MB):
    // [0, 400128)            csr_ptr (N+1 ints)
    // [400128, 800256)       cursor  (N ints; degrees, then fill cursors)
    // [800256, 7200256)      csr_src (E ints)
    // [7200256, +40MB)       h1b (N x 200 bf16)
    // [47200256, +80MB)      h2  (N x 200 fp32)
    // bsums (98 ints) aliases the h1b region: dead before gin_layer1 writes it.
    char* ws = (char*)d_ws;
    int* csr_ptr = (int*)(ws + 0);
    int* cursor  = (int*)(ws + 400128);
    int* csr_src = (int*)(ws + 800256);
    __hip_bfloat16* h1b = (__hip_bfloat16*)(ws + 7200256);
    float* h2    = (float*)(ws + 47200256);
    int* bsums   = (int*)(ws + 7200256);   // alias, scan-time only

    hipMemsetAsync(cursor, 0, N_NODES * sizeof(int), stream);
    hist_kernel<<<(N_EDGES + 255) / 256, 256, 0, stream>>>(ei, cursor);
    scan_part<<<NB_SCAN, 256, 0, stream>>>(cursor, bsums);
    scan_tops<<<1, 128, 0, stream>>>(bsums, csr_ptr);
    scan_fin<<<NB_SCAN, 256, 0, stream>>>(cursor, bsums, csr_ptr);
    fill_kernel<<<(N_EDGES + 255) / 256, 256, 0, stream>>>(ei, cursor, csr_src);

    gin_layer1<<<N_NODES / 32, 256, 0, stream>>>(x, csr_ptr, csr_src,
            eps1, W1a, b1a, W1b, b1b, bn1g, bn1b, bn1m, bn1v, h1b);
    gin_layer2<<<N_NODES / 32, 256, 0, stream>>>(h1b, csr_ptr, csr_src,
            eps2, W2a, b2a, W2b, b2b, bn2g, bn2b, bn2m, bn2v, h2);

    pool_fc_kernel<<<N_GRAPHS, 256, 0, stream>>>(h2, batch, Wfc, bfc, out);
}

// Round 5
// 901.447 us; speedup vs baseline: 1.5527x; 1.0360x over previous
//
#include <hip/hip_runtime.h>
#include <hip/hip_bf16.h>
#include <math.h>

#define N_NODES 100000
#define N_EDGES 1600000
#define F_IN 64
#define H_DIM 200
#define N_GRAPHS 512
#define NB_SCAN 98   // ceil(100000 / 1024)

#define WT_PER (224 * 224)   // one padded weight table (shorts)
#define SA 232               // LDS A-tile stride (shorts)

typedef __attribute__((ext_vector_type(8))) short short8v;   // 8 bf16 = 4 VGPR
typedef __attribute__((ext_vector_type(4))) float f32x4;     // mfma accumulator

// ---------------- CSR build: histogram by dst ----------------
__global__ void hist_kernel(const int* __restrict__ ei, int* __restrict__ cnt) {
    int i = blockIdx.x * blockDim.x + threadIdx.x;
    if (i < N_EDGES) atomicAdd(&cnt[ei[N_EDGES + i]], 1);
}

__global__ __launch_bounds__(256) void scan_part(const int* __restrict__ deg,
                                                 int* __restrict__ bsums) {
    int b = blockIdx.x, t = threadIdx.x;
    int i0 = b * 1024 + t * 4;
    int s = 0;
    #pragma unroll
    for (int k = 0; k < 4; ++k) { int i = i0 + k; if (i < N_NODES) s += deg[i]; }
    #pragma unroll
    for (int off = 32; off > 0; off >>= 1) s += __shfl_down(s, off, 64);
    __shared__ int wsum[4];
    if ((t & 63) == 0) wsum[t >> 6] = s;
    __syncthreads();
    if (t == 0) bsums[b] = wsum[0] + wsum[1] + wsum[2] + wsum[3];
}

__global__ void scan_tops(int* __restrict__ bsums, int* __restrict__ ptr) {
    __shared__ int sh[128];
    int t = threadIdx.x;
    int v = (t < NB_SCAN) ? bsums[t] : 0;
    sh[t] = v;
    __syncthreads();
    for (int off = 1; off < 128; off <<= 1) {
        int a = sh[t];
        int add = (t >= off) ? sh[t - off] : 0;
        __syncthreads();
        sh[t] = a + add;
        __syncthreads();
    }
    if (t < NB_SCAN) bsums[t] = sh[t] - v;
    if (t == 127) ptr[N_NODES] = sh[127];
}

__global__ __launch_bounds__(256) void scan_fin(int* __restrict__ deg_cursor,
                                                const int* __restrict__ bsums,
                                                int* __restrict__ ptr) {
    int b = blockIdx.x, t = threadIdx.x;
    int i0 = b * 1024 + t * 4;
    int d[4]; int s = 0;
    #pragma unroll
    for (int k = 0; k < 4; ++k) {
        int i = i0 + k;
        d[k] = (i < N_NODES) ? deg_cursor[i] : 0;
        s += d[k];
    }
    __shared__ int sh[256];
    sh[t] = s;
    __syncthreads();
    for (int off = 1; off < 256; off <<= 1) {
        int a = sh[t];
        int add = (t >= off) ? sh[t - off] : 0;
        __syncthreads();
        sh[t] = a + add;
        __syncthreads();
    }
    int run = bsums[b] + sh[t] - s;
    #pragma unroll
    for (int k = 0; k < 4; ++k) {
        int i = i0 + k;
        if (i < N_NODES) { ptr[i] = run; deg_cursor[i] = run; run += d[k]; }
    }
}

__global__ void fill_kernel(const int* __restrict__ ei, int* __restrict__ cursor,
                            int* __restrict__ csr_src) {
    int i = blockIdx.x * blockDim.x + threadIdx.x;
    if (i < N_EDGES) {
        int s = ei[i];
        int d = ei[N_EDGES + i];
        int p = atomicAdd(&cursor[d], 1);
        csr_src[p] = s;
    }
}

// helpers
__device__ __forceinline__ short f2bf(float f) {
    __hip_bfloat16 h = __float2bfloat16(f);
    return *reinterpret_cast<const short*>(&h);
}
__device__ __forceinline__ float bf2f(short s) {
    return __uint_as_float(((unsigned)(unsigned short)s) << 16);
}
__device__ __forceinline__ float4 bf4_to_f4(uint2 u) {
    float4 r;
    r.x = __uint_as_float(u.x << 16);
    r.y = __uint_as_float(u.x & 0xffff0000u);
    r.z = __uint_as_float(u.y << 16);
    r.w = __uint_as_float(u.y & 0xffff0000u);
    return r;
}

// ---------------- weight prep: W[K][200] fp32 -> hi/lo bf16 tables [224 cols][224 k] ----------------
// table layout: for matrix m: hi at wt + (2m)*WT_PER, lo at wt + (2m+1)*WT_PER
__global__ void prep_w(const float* __restrict__ W1a, const float* __restrict__ W1b,
                       const float* __restrict__ W2a, const float* __restrict__ W2b,
                       short* __restrict__ wt) {
    int idx = blockIdx.x * 256 + threadIdx.x;
    if (idx >= 4 * WT_PER) return;
    int tsel = idx / WT_PER, rem = idx % WT_PER;
    int c = rem / 224, k = rem % 224;
    const float* W = (tsel == 0) ? W1a : (tsel == 1) ? W1b : (tsel == 2) ? W2a : W2b;
    int K = (tsel == 0) ? 64 : 200;
    float v = (k < K && c < 200) ? W[k * 200 + c] : 0.0f;   // pads MUST be zero
    short hi = f2bf(v);
    short lo = f2bf(v - bf2f(hi));
    wt[(2 * tsel) * WT_PER + rem] = hi;
    wt[(2 * tsel + 1) * WT_PER + rem] = lo;
}

// ---- split-bf16 MFMA tile GEMM ----
// A: row=l&15, k=8*(l>>4)+j ; B: col=l&15, same k ; acc: col=l&15, row=(l>>4)*4+i
// acc += Ah*Bh + Ah*Bl + Al*Bh  (Al*Bl dropped, ~2^-16 relative)
template <int NKS>
__device__ __forceinline__ void gemm_split(const short* __restrict__ SLh,
                                           const short* __restrict__ SLl,
                                           const short* __restrict__ Wh,
                                           const short* __restrict__ Wl,
                                           int l15, int lhi, int rt, int ch,
                                           f32x4 acc[7]) {
    for (int ks = 0; ks < NKS; ++ks) {
        const int k0 = ks * 32 + 8 * lhi;
        short8v ah = *reinterpret_cast<const short8v*>(SLh + (rt * 16 + l15) * SA + k0);
        short8v al = *reinterpret_cast<const short8v*>(SLl + (rt * 16 + l15) * SA + k0);
        #pragma unroll
        for (int ct = 0; ct < 7; ++ct) {
            const int wrow = (ch * 7 + ct) * 16 + l15;
            short8v bh = *reinterpret_cast<const short8v*>(Wh + wrow * 224 + k0);
            short8v bl = *reinterpret_cast<const short8v*>(Wl + wrow * 224 + k0);
            acc[ct] = __builtin_amdgcn_mfma_f32_16x16x32_bf16(ah, bh, acc[ct], 0, 0, 0);
            acc[ct] = __builtin_amdgcn_mfma_f32_16x16x32_bf16(ah, bl, acc[ct], 0, 0, 0);
            acc[ct] = __builtin_amdgcn_mfma_f32_16x16x32_bf16(al, bh, acc[ct], 0, 0, 0);
        }
    }
}

// ---------------- fused GIN layer: gather -> split-MFMA GEMM1 -> relu -> GEMM2 -> BN ----------------
// 512 threads = 8 waves; 64 nodes/block. Gather: wave handles 8 rows, 8-deep ILP.
// GEMM: wave (rt = wid>>1) x (col-half ch = wid&1, 7 tiles each).
template <bool FIRST>
__global__ __launch_bounds__(512, 4) void gin_mfma(
        const void* __restrict__ Xv,                 // fp32 [N][64] or bf16 [N][200]
        const int* __restrict__ ptr, const int* __restrict__ srcl,
        const float* __restrict__ eps_p,
        const short* __restrict__ Wa2,               // hi table; lo at +WT_PER
        const float* __restrict__ ba,
        const short* __restrict__ Wb2, const float* __restrict__ bb,
        const float* __restrict__ gamma, const float* __restrict__ beta,
        const float* __restrict__ mean, const float* __restrict__ var,
        void* __restrict__ outv) {                   // bf16 [N][200] or fp32 [N][200]
    __shared__ __align__(16) short SLh[64 * SA];     // 29,696 B
    __shared__ __align__(16) short SLl[64 * SA];     // 29,696 B
    const int t = threadIdx.x;
    const int lane = t & 63;
    const int wid = t >> 6;
    const int node0 = blockIdx.x * 64;
    const float ep = 1.0f + eps_p[0];

    // ---- zero the k-pad cols [200,232) so garbage never reaches MFMA ----
    for (int i = t; i < 64 * 32; i += 512) {
        int row = i >> 5, c = 200 + (i & 31);
        SLh[row * SA + c] = 0;
        SLl[row * SA + c] = 0;
    }

    // ---- gather phase ----
    if (FIRST) {
        const float* X = (const float*)Xv;
        for (int rr = 0; rr < 8; ++rr) {
            int row = wid * 8 + rr;
            int node = node0 + row;
            if (node >= N_NODES) break;
            int b = ptr[node], e = ptr[node + 1];
            float a0 = ep * X[(size_t)node * 64 + lane];
            float a1 = 0.f, a2 = 0.f, a3 = 0.f, a4 = 0.f, a5 = 0.f, a6 = 0.f, a7 = 0.f;
            int j = b;
            for (; j + 8 <= e; j += 8) {
                int s0 = srcl[j+0], s1 = srcl[j+1], s2 = srcl[j+2], s3 = srcl[j+3];
                int s4 = srcl[j+4], s5 = srcl[j+5], s6 = srcl[j+6], s7 = srcl[j+7];
                a0 += X[(size_t)s0 * 64 + lane];
                a1 += X[(size_t)s1 * 64 + lane];
                a2 += X[(size_t)s2 * 64 + lane];
                a3 += X[(size_t)s3 * 64 + lane];
                a4 += X[(size_t)s4 * 64 + lane];
                a5 += X[(size_t)s5 * 64 + lane];
                a6 += X[(size_t)s6 * 64 + lane];
                a7 += X[(size_t)s7 * 64 + lane];
            }
            if (j + 4 <= e) {
                int s0 = srcl[j+0], s1 = srcl[j+1], s2 = srcl[j+2], s3 = srcl[j+3];
                a0 += X[(size_t)s0 * 64 + lane];
                a1 += X[(size_t)s1 * 64 + lane];
                a2 += X[(size_t)s2 * 64 + lane];
                a3 += X[(size_t)s3 * 64 + lane];
                j += 4;
            }
            for (; j < e; ++j) a0 += X[(size_t)srcl[j] * 64 + lane];
            float s = ((a0 + a1) + (a2 + a3)) + ((a4 + a5) + (a6 + a7));
            short hi = f2bf(s);
            SLh[row * SA + lane] = hi;               // k = lane < 64
            SLl[row * SA + lane] = f2bf(s - bf2f(hi));
        }
    } else {
        const uint2* H2 = (const uint2*)Xv;          // bf16 rows: 50 x uint2
        for (int rr = 0; rr < 8; ++rr) {
            int row = wid * 8 + rr;
            int node = node0 + row;
            if (node >= N_NODES) break;
            int b = ptr[node], e = ptr[node + 1];
            if (lane < 50) {
                uint2 us = H2[(size_t)node * 50 + lane];
                float4 fs = bf4_to_f4(us);
                float4 A0 = make_float4(ep * fs.x, ep * fs.y, ep * fs.z, ep * fs.w);
                float4 A1 = make_float4(0,0,0,0), A2 = make_float4(0,0,0,0);
                float4 A3 = make_float4(0,0,0,0), A4 = make_float4(0,0,0,0);
                float4 A5 = make_float4(0,0,0,0), A6 = make_float4(0,0,0,0);
                float4 A7 = make_float4(0,0,0,0);
                int j = b;
                for (; j + 8 <= e; j += 8) {
                    int s0 = srcl[j+0], s1 = srcl[j+1], s2 = srcl[j+2], s3 = srcl[j+3];
                    int s4 = srcl[j+4], s5 = srcl[j+5], s6 = srcl[j+6], s7 = srcl[j+7];
                    float4 f0 = bf4_to_f4(H2[(size_t)s0 * 50 + lane]);
                    float4 f1 = bf4_to_f4(H2[(size_t)s1 * 50 + lane]);
                    float4 f2 = bf4_to_f4(H2[(size_t)s2 * 50 + lane]);
                    float4 f3 = bf4_to_f4(H2[(size_t)s3 * 50 + lane]);
                    float4 f4 = bf4_to_f4(H2[(size_t)s4 * 50 + lane]);
                    float4 f5 = bf4_to_f4(H2[(size_t)s5 * 50 + lane]);
                    float4 f6 = bf4_to_f4(H2[(size_t)s6 * 50 + lane]);
                    float4 f7 = bf4_to_f4(H2[(size_t)s7 * 50 + lane]);
                    A0.x += f0.x; A0.y += f0.y; A0.z += f0.z; A0.w += f0.w;
                    A1.x += f1.x; A1.y += f1.y; A1.z += f1.z; A1.w += f1.w;
                    A2.x += f2.x; A2.y += f2.y; A2.z += f2.z; A2.w += f2.w;
                    A3.x += f3.x; A3.y += f3.y; A3.z += f3.z; A3.w += f3.w;
                    A4.x += f4.x; A4.y += f4.y; A4.z += f4.z; A4.w += f4.w;
                    A5.x += f5.x; A5.y += f5.y; A5.z += f5.z; A5.w += f5.w;
                    A6.x += f6.x; A6.y += f6.y; A6.z += f6.z; A6.w += f6.w;
                    A7.x += f7.x; A7.y += f7.y; A7.z += f7.z; A7.w += f7.w;
                }
                if (j + 4 <= e) {
                    int s0 = srcl[j+0], s1 = srcl[j+1], s2 = srcl[j+2], s3 = srcl[j+3];
                    float4 f0 = bf4_to_f4(H2[(size_t)s0 * 50 + lane]);
                    float4 f1 = bf4_to_f4(H2[(size_t)s1 * 50 + lane]);
                    float4 f2 = bf4_to_f4(H2[(size_t)s2 * 50 + lane]);
                    float4 f3 = bf4_to_f4(H2[(size_t)s3 * 50 + lane]);
                    A0.x += f0.x; A0.y += f0.y; A0.z += f0.z; A0.w += f0.w;
                    A1.x += f1.x; A1.y += f1.y; A1.z += f1.z; A1.w += f1.w;
                    A2.x += f2.x; A2.y += f2.y; A2.z += f2.z; A2.w += f2.w;
                    A3.x += f3.x; A3.y += f3.y; A3.z += f3.z; A3.w += f3.w;
                    j += 4;
                }
                for (; j < e; ++j) {
                    float4 f0 = bf4_to_f4(H2[(size_t)srcl[j] * 50 + lane]);
                    A0.x += f0.x; A0.y += f0.y; A0.z += f0.z; A0.w += f0.w;
                }
                float sx = ((A0.x + A1.x) + (A2.x + A3.x)) + ((A4.x + A5.x) + (A6.x + A7.x));
                float sy = ((A0.y + A1.y) + (A2.y + A3.y)) + ((A4.y + A5.y) + (A6.y + A7.y));
                float sz = ((A0.z + A1.z) + (A2.z + A3.z)) + ((A4.z + A5.z) + (A6.z + A7.z));
                float sw = ((A0.w + A1.w) + (A2.w + A3.w)) + ((A4.w + A5.w) + (A6.w + A7.w));
                short4 ph, pl;
                ph.x = f2bf(sx); pl.x = f2bf(sx - bf2f(ph.x));
                ph.y = f2bf(sy); pl.y = f2bf(sy - bf2f(ph.y));
                ph.z = f2bf(sz); pl.z = f2bf(sz - bf2f(ph.z));
                ph.w = f2bf(sw); pl.w = f2bf(sw - bf2f(ph.w));
                *reinterpret_cast<short4*>(&SLh[row * SA + 4 * lane]) = ph;
                *reinterpret_cast<short4*>(&SLl[row * SA + 4 * lane]) = pl;
            }
        }
    }
    __syncthreads();

    const int l15 = lane & 15;
    const int lhi = lane >> 4;
    const int rt = wid >> 1;     // row-tile 0..3
    const int ch = wid & 1;      // column half

    // ---- GEMM1 ----
    f32x4 acc1[7];
    #pragma unroll
    for (int ct = 0; ct < 7; ++ct) acc1[ct] = (f32x4){0.f, 0.f, 0.f, 0.f};
    if (FIRST) gemm_split<2>(SLh, SLl, Wa2, Wa2 + WT_PER, l15, lhi, rt, ch, acc1);
    else       gemm_split<7>(SLh, SLl, Wa2, Wa2 + WT_PER, l15, lhi, rt, ch, acc1);
    __syncthreads();   // all A1 reads done before overwrite

    // ---- t = relu(acc1 + ba) -> SLh/SLl (cols < 200; pads still zero) ----
    #pragma unroll
    for (int ct = 0; ct < 7; ++ct) {
        int col = (ch * 7 + ct) * 16 + l15;
        if (col < 200) {
            float bv = ba[col];
            #pragma unroll
            for (int i = 0; i < 4; ++i) {
                int row = rt * 16 + lhi * 4 + i;
                float v = fmaxf(acc1[ct][i] + bv, 0.0f);
                short hi = f2bf(v);
                SLh[row * SA + col] = hi;
                SLl[row * SA + col] = f2bf(v - bf2f(hi));
            }
        }
    }
    __syncthreads();

    // ---- GEMM2 (K = 200 both layers) ----
    f32x4 acc2[7];
    #pragma unroll
    for (int ct = 0; ct < 7; ++ct) acc2[ct] = (f32x4){0.f, 0.f, 0.f, 0.f};
    gemm_split<7>(SLh, SLl, Wb2, Wb2 + WT_PER, l15, lhi, rt, ch, acc2);

    // ---- epilogue: relu + BN -> out ----
    #pragma unroll
    for (int ct = 0; ct < 7; ++ct) {
        int col = (ch * 7 + ct) * 16 + l15;
        if (col >= 200) continue;
        float bv = bb[col];
        float g0 = gamma[col], bt = beta[col], mn = mean[col];
        float inv = rsqrtf(var[col] + 1e-5f);
        #pragma unroll
        for (int i = 0; i < 4; ++i) {
            int row = rt * 16 + lhi * 4 + i;
            int node = node0 + row;
            if (node < N_NODES) {
                float v = fmaxf(acc2[ct][i] + bv, 0.0f);
                v = (v - mn) * inv * g0 + bt;
                if (FIRST) ((__hip_bfloat16*)outv)[(size_t)node * 200 + col] = __float2bfloat16(v);
                else       ((float*)outv)[(size_t)node * 200 + col] = v;
            }
        }
    }
}

// ---------------- fused pooling (sum+max) + FC + log_softmax ----------------
__device__ __forceinline__ int lower_bound_dev(const int* a, int n, int v) {
    int lo = 0, hi = n;
    while (lo < hi) { int mid = (lo + hi) >> 1; if (a[mid] < v) lo = mid + 1; else hi = mid; }
    return lo;
}

__global__ __launch_bounds__(256) void pool_fc_kernel(const float* __restrict__ h,
        const int* __restrict__ batch, const float* __restrict__ Wfc,
        const float* __restrict__ bfc, float* __restrict__ out) {
    int g = blockIdx.x;
    __shared__ int range[2];
    if (threadIdx.x == 0) range[0] = lower_bound_dev(batch, N_NODES, g);
    else if (threadIdx.x == 64) range[1] = lower_bound_dev(batch, N_NODES, g + 1);
    __syncthreads();
    int b = range[0], e = range[1];
    int d = threadIdx.x;
    float s = 0.0f, m = -3.0e38f;
    for (int n = b; n < e; ++n) {
        if (d < 200) {
            float v = h[(size_t)n * 200 + d];
            s += v;
            m = fmaxf(m, v);
        }
    }
    float c0 = 0.f, c1 = 0.f;
    if (d < 200) {
        c0 = s * Wfc[d * 2 + 0] + m * Wfc[(200 + d) * 2 + 0];
        c1 = s * Wfc[d * 2 + 1] + m * Wfc[(200 + d) * 2 + 1];
    }
    #pragma unroll
    for (int off = 32; off > 0; off >>= 1) {
        c0 += __shfl_down(c0, off, 64);
        c1 += __shfl_down(c1, off, 64);
    }
    __shared__ float r0[4], r1[4];
    int wid = threadIdx.x >> 6;
    if ((threadIdx.x & 63) == 0) { r0[wid] = c0; r1[wid] = c1; }
    __syncthreads();
    if (threadIdx.x == 0) {
        float l0 = r0[0] + r0[1] + r0[2] + r0[3] + bfc[0];
        float l1 = r1[0] + r1[1] + r1[2] + r1[3] + bfc[1];
        float mx = fmaxf(l0, l1);
        float lse = mx + logf(expf(l0 - mx) + expf(l1 - mx));
        out[g * 2 + 0] = l0 - lse;
        out[g * 2 + 1] = l1 - lse;
    }
}

// ---------------- launch ----------------
extern "C" void kernel_launch(void* const* d_in, const int* in_sizes, int n_in,
                              void* d_out, int out_size, void* d_ws, size_t ws_size,
                              hipStream_t stream) {
    const float* x    = (const float*)d_in[0];
    const int*   ei   = (const int*)d_in[1];
    const int*   batch= (const int*)d_in[2];
    const float* eps1 = (const float*)d_in[3];
    const float* W1a  = (const float*)d_in[4];
    const float* b1a  = (const float*)d_in[5];
    const float* W1b  = (const float*)d_in[6];
    const float* b1b  = (const float*)d_in[7];
    const float* bn1g = (const float*)d_in[8];
    const float* bn1b = (const float*)d_in[9];
    const float* bn1m = (const float*)d_in[10];
    const float* bn1v = (const float*)d_in[11];
    const float* eps2 = (const float*)d_in[12];
    const float* W2a  = (const float*)d_in[13];
    const float* b2a  = (const float*)d_in[14];
    const float* W2b  = (const float*)d_in[15];
    const float* b2b  = (const float*)d_in[16];
    const float* bn2g = (const float*)d_in[17];
    const float* bn2b = (const float*)d_in[18];
    const float* bn2m = (const float*)d_in[19];
    const float* bn2v = (const float*)d_in[20];
    const float* Wfc  = (const float*)d_in[21];
    const float* bfc  = (const float*)d_in[22];
    float* out = (float*)d_out;

    // workspace layout:
    // [0, 400128)              csr_ptr (N+1 ints)
    // [400128, 800256)         cursor
    // [800256, 7200256)        csr_src (E ints)
    // [7200256, 8003072)       wt: 8 bf16 tables [224][224] (hi/lo x 4 matrices)
    // [8003072, 48003072)      h1b (N x 200 bf16)
    // [48003072, 128003072)    h2  (N x 200 fp32)
    char* ws = (char*)d_ws;
    int* csr_ptr = (int*)(ws + 0);
    int* cursor  = (int*)(ws + 400128);
    int* csr_src = (int*)(ws + 800256);
    short* wt    = (short*)(ws + 7200256);
    short* W1a2 = wt;                    // hi; lo at +WT_PER
    short* W1b2 = wt + 2 * WT_PER;
    short* W2a2 = wt + 4 * WT_PER;
    short* W2b2 = wt + 6 * WT_PER;
    __hip_bfloat16* h1b = (__hip_bfloat16*)(ws + 8003072);
    float* h2    = (float*)(ws + 48003072);
    int* bsums   = (int*)(ws + 8003072);   // alias h1b: dead until layer1 writes

    hipMemsetAsync(cursor, 0, N_NODES * sizeof(int), stream);
    hist_kernel<<<(N_EDGES + 255) / 256, 256, 0, stream>>>(ei, cursor);
    scan_part<<<NB_SCAN, 256, 0, stream>>>(cursor, bsums);
    scan_tops<<<1, 128, 0, stream>>>(bsums, csr_ptr);
    scan_fin<<<NB_SCAN, 256, 0, stream>>>(cursor, bsums, csr_ptr);
    fill_kernel<<<(N_EDGES + 255) / 256, 256, 0, stream>>>(ei, cursor, csr_src);
    prep_w<<<(4 * WT_PER + 255) / 256, 256, 0, stream>>>(W1a, W1b, W2a, W2b, wt);

    const int NBLK = (N_NODES + 63) / 64;   // 1563
    gin_mfma<true><<<NBLK, 512, 0, stream>>>(x, csr_ptr, csr_src, eps1,
            W1a2, b1a, W1b2, b1b, bn1g, bn1b, bn1m, bn1v, h1b);
    gin_mfma<false><<<NBLK, 512, 0, stream>>>(h1b, csr_ptr, csr_src, eps2,
            W2a2, b2a, W2b2, b2b, bn2g, bn2b, bn2m, bn2v, h2);

    pool_fc_kernel<<<N_GRAPHS, 256, 0, stream>>>(h2, batch, Wfc, bfc, out);
}